// Round 1
// baseline (467.621 us; speedup 1.0000x reference)
//
#include <hip/hip_runtime.h>
#include <hip/hip_bf16.h>

#define N 8192
#define DIN 64
#define DOUT 128
#define KNN 16
#define NCHUNK 16
#define CHUNK 512   /* N / NCHUNK */
#define TJ 128

typedef unsigned long long u64;

__device__ __forceinline__ unsigned mono(float f) {
    unsigned u = __float_as_uint(f);
    return (u & 0x80000000u) ? ~u : (u | 0x80000000u);
}

// K1: squared norms, accumulation order bit-identical to k_dist_topk's dot
__global__ __launch_bounds__(256) void k_sq(const float* __restrict__ x,
                                            float* __restrict__ sq) {
    int i = blockIdx.x * 256 + threadIdx.x;
    const float4* x4 = (const float4*)x + (size_t)i * (DIN / 4);
    float s0 = 0.f, s1 = 0.f, s2 = 0.f, s3 = 0.f;
#pragma unroll
    for (int q = 0; q < DIN / 4; ++q) {
        float4 a = x4[q];
        s0 = fmaf(a.x, a.x, s0); s1 = fmaf(a.y, a.y, s1);
        s2 = fmaf(a.z, a.z, s2); s3 = fmaf(a.w, a.w, s3);
    }
    sq[i] = (s0 + s1) + (s2 + s3);
}

// K2: fused distance + per-thread top-16 over one j-chunk.
// grid: (NCHUNK, N/256). Each thread owns one row i, scans CHUNK j's.
// Keys are ((monotonic dist bits)<<32)|j so ordering == (dist asc, j asc),
// matching lax.top_k tie-breaking exactly.
__global__ __launch_bounds__(256) void k_dist_topk(const float* __restrict__ x,
                                                   const float* __restrict__ sq,
                                                   u64* __restrict__ pkeys) {
    __shared__ float4 xjs[TJ * (DIN / 4)];
    __shared__ float sqj[TJ];
    int t = threadIdx.x;
    int chunk = blockIdx.x;
    int row = blockIdx.y * 256 + t;
    const float4* x4 = (const float4*)x;

    float4 xi[DIN / 4];
#pragma unroll
    for (int q = 0; q < DIN / 4; ++q) xi[q] = x4[(size_t)row * 16 + q];
    float sqi = sq[row];

    u64 keys[KNN];
#pragma unroll
    for (int s = 0; s < KNN; ++s) keys[s] = 0xFFFFFFFFFFFFFFFFull - (u64)s;
    u64 kmax = 0xFFFFFFFFFFFFFFFFull;

    int j0 = chunk * CHUNK;
    for (int tile = 0; tile < CHUNK / TJ; ++tile) {
        int jb = j0 + tile * TJ;
        __syncthreads();
#pragma unroll
        for (int u = 0; u < (TJ * (DIN / 4)) / 256; ++u) {
            int v = t + u * 256;                 // v = jr*16 + q
            xjs[v] = x4[(size_t)jb * 16 + v];
        }
        if (t < TJ) sqj[t] = sq[jb + t];
        __syncthreads();

        for (int jj = 0; jj < TJ; ++jj) {
            float s0 = 0.f, s1 = 0.f, s2 = 0.f, s3 = 0.f;
#pragma unroll
            for (int q = 0; q < DIN / 4; ++q) {
                float4 a = xi[q];
                float4 b = xjs[jj * 16 + q];     // wave-uniform addr -> broadcast
                s0 = fmaf(a.x, b.x, s0); s1 = fmaf(a.y, b.y, s1);
                s2 = fmaf(a.z, b.z, s2); s3 = fmaf(a.w, b.w, s3);
            }
            float d = (s0 + s1) + (s2 + s3);
            float dist = sqi + sqj[jj] - 2.0f * d;
            int j = jb + jj;
            u64 key = ((u64)mono(dist) << 32) | (unsigned)j;
            if (key < kmax) {
                // replace current max slot (keys unique -> exactly one match)
#pragma unroll
                for (int s = 0; s < KNN; ++s)
                    if (keys[s] == kmax) keys[s] = key;
                u64 m = keys[0];
#pragma unroll
                for (int s = 1; s < KNN; ++s) m = keys[s] > m ? keys[s] : m;
                kmax = m;
            }
        }
    }
#pragma unroll
    for (int s = 0; s < KNN; ++s)
        pkeys[(size_t)row * (NCHUNK * KNN) + chunk * KNN + s] = keys[s];
}

// K3: merge 256 candidates/row -> final 16 indices. One wave per row.
__global__ __launch_bounds__(256) void k_merge(const u64* __restrict__ pkeys,
                                               int* __restrict__ knn) {
    int wave = threadIdx.x >> 6, lane = threadIdx.x & 63;
    int row = blockIdx.x * 4 + wave;
    u64 k[4];
#pragma unroll
    for (int u = 0; u < 4; ++u)
        k[u] = pkeys[(size_t)row * 256 + lane + 64 * u];
#pragma unroll
    for (int t = 0; t < KNN; ++t) {
        u64 m = k[0];
#pragma unroll
        for (int u = 1; u < 4; ++u) m = (k[u] < m) ? k[u] : m;
#pragma unroll
        for (int off = 32; off >= 1; off >>= 1) {
            u64 o = __shfl_xor(m, off, 64);
            m = (o < m) ? o : m;
        }
        if (lane == t) knn[row * KNN + t] = (int)(unsigned)(m & 0xFFFFFFFFull);
#pragma unroll
        for (int u = 0; u < 4; ++u)
            if (k[u] == m) k[u] = 0xFFFFFFFFFFFFFFFFull;
    }
}

// K4: U = x @ (W1a - W1b) + b1,  V = x @ W1b.  16 rows / block.
__global__ __launch_bounds__(256) void k_uv(const float* __restrict__ x,
                                            const float* __restrict__ W1,
                                            const float* __restrict__ b1,
                                            float* __restrict__ U,
                                            float* __restrict__ V) {
    __shared__ float xs[16][DIN];
    int t = threadIdx.x;
    int r0 = blockIdx.x * 16;
    const float4* x4 = (const float4*)x;
    ((float4*)xs)[t] = x4[(size_t)r0 * 16 + t];
    __syncthreads();
    int o = t & 127, g = t >> 7;
    float aU[8], aV[8];
#pragma unroll
    for (int u = 0; u < 8; ++u) { aU[u] = 0.f; aV[u] = 0.f; }
    for (int kk = 0; kk < DIN; ++kk) {
        float whi = W1[kk * DOUT + o];
        float wlo = W1[(DIN + kk) * DOUT + o];
        float wd = whi - wlo;
#pragma unroll
        for (int u = 0; u < 8; ++u) {
            float xv = xs[g * 8 + u][kk];
            aU[u] = fmaf(xv, wd, aU[u]);
            aV[u] = fmaf(xv, wlo, aV[u]);
        }
    }
    float bb = b1[o];
#pragma unroll
    for (int u = 0; u < 8; ++u) {
        int r = r0 + g * 8 + u;
        U[(size_t)r * DOUT + o] = aU[u] + bb;
        V[(size_t)r * DOUT + o] = aV[u];
    }
}

// K5a: agg[i] = mean_j relu(U[i] + V[knn[i][j]])
__global__ __launch_bounds__(256) void k_agg(const float* __restrict__ U,
                                             const float* __restrict__ V,
                                             const int* __restrict__ knn,
                                             float* __restrict__ agg) {
    int t = threadIdx.x;
    int i = blockIdx.x * 2 + (t >> 7);
    int o = t & 127;
    float u = U[(size_t)i * DOUT + o];
    const int* nb = knn + i * KNN;
    float acc = 0.f;
#pragma unroll
    for (int q = 0; q < KNN; ++q) {
        int j = nb[q];
        float v = V[(size_t)j * DOUT + o];
        acc += fmaxf(u + v, 0.0f);
    }
    agg[(size_t)i * DOUT + o] = acc * (1.0f / KNN);
}

// K5b: out = agg @ W2 + b2.  32 rows / block.
__global__ __launch_bounds__(256) void k_out(const float* __restrict__ agg,
                                             const float* __restrict__ W2,
                                             const float* __restrict__ b2,
                                             float* __restrict__ out) {
    __shared__ float ag[32][DOUT];
    int t = threadIdx.x;
    int r0 = blockIdx.x * 32;
    const float4* a4 = (const float4*)(agg + (size_t)r0 * DOUT);
    float4* s4 = (float4*)ag;
#pragma unroll
    for (int u = 0; u < 4; ++u) s4[t + u * 256] = a4[t + u * 256];
    __syncthreads();
    int o = t & 127, g = t >> 7;
    float acc[16];
#pragma unroll
    for (int u = 0; u < 16; ++u) acc[u] = 0.f;
    for (int kk = 0; kk < DOUT; ++kk) {
        float w = W2[kk * DOUT + o];
#pragma unroll
        for (int u = 0; u < 16; ++u)
            acc[u] = fmaf(ag[g * 16 + u][kk], w, acc[u]);
    }
    float bb = b2[o];
#pragma unroll
    for (int u = 0; u < 16; ++u)
        out[(size_t)(r0 + g * 16 + u) * DOUT + o] = acc[u] + bb;
}

extern "C" void kernel_launch(void* const* d_in, const int* in_sizes, int n_in,
                              void* d_out, int out_size, void* d_ws, size_t ws_size,
                              hipStream_t stream) {
    const float* x  = (const float*)d_in[0];
    const float* W1 = (const float*)d_in[1];
    const float* b1 = (const float*)d_in[2];
    const float* W2 = (const float*)d_in[3];
    const float* b2 = (const float*)d_in[4];
    float* out = (float*)d_out;

    char* ws = (char*)d_ws;
    float* sq   = (float*)ws;                                   // 32 KB
    u64*   pkeys = (u64*)(ws + 32768);                          // 16 MB
    float* U    = (float*)(ws + 32768 + (size_t)16 * 1024 * 1024);
    float* V    = U + (size_t)N * DOUT;                         // 4 MB each
    int*   knn  = (int*)(V + (size_t)N * DOUT);                 // 512 KB
    float* agg  = (float*)(knn + (size_t)N * KNN);              // 4 MB
    // total ws use ~28.5 MB

    k_sq<<<N / 256, 256, 0, stream>>>(x, sq);
    k_dist_topk<<<dim3(NCHUNK, N / 256), 256, 0, stream>>>(x, sq, pkeys);
    k_merge<<<N / 4, 256, 0, stream>>>(pkeys, knn);
    k_uv<<<N / 16, 256, 0, stream>>>(x, W1, b1, U, V);
    k_agg<<<N / 2, 256, 0, stream>>>(U, V, knn, agg);
    k_out<<<N / 32, 256, 0, stream>>>(agg, W2, b2, out);
}

// Round 2
// 464.981 us; speedup vs baseline: 1.0057x; 1.0057x over previous
//
#include <hip/hip_runtime.h>

#define N 8192
#define DIN 64
#define DOUT 128
#define KNN 16
#define NCHUNK 32
#define CHUNK 256          /* N / NCHUNK */
#define ROWS_PRE 16

typedef unsigned long long u64;

__device__ __forceinline__ unsigned mono(float f) {
    unsigned u = __float_as_uint(f);
    return (u & 0x80000000u) ? ~u : (u | 0x80000000u);
}

// K1: sq norms + U = x@(W1a-W1b)+b1, V = x@W1b (16 rows/block)
__global__ __launch_bounds__(256) void k_pre(const float* __restrict__ x,
                                             const float* __restrict__ W1,
                                             const float* __restrict__ b1,
                                             float* __restrict__ sq,
                                             float* __restrict__ U,
                                             float* __restrict__ V) {
    __shared__ float xs[ROWS_PRE][DIN];
    int t = threadIdx.x;
    int r0 = blockIdx.x * ROWS_PRE;
    const float4* x4 = (const float4*)x;
    ((float4*)xs)[t] = x4[(size_t)r0 * (DIN / 4) + t];
    __syncthreads();
    if (t < ROWS_PRE) {
        const float4* xr = (const float4*)xs[t];
        float s0 = 0.f, s1 = 0.f, s2 = 0.f, s3 = 0.f;
#pragma unroll
        for (int q = 0; q < DIN / 4; ++q) {
            float4 a = xr[q];
            s0 = fmaf(a.x, a.x, s0); s1 = fmaf(a.y, a.y, s1);
            s2 = fmaf(a.z, a.z, s2); s3 = fmaf(a.w, a.w, s3);
        }
        sq[r0 + t] = (s0 + s1) + (s2 + s3);
    }
    int o = t & 127, g = t >> 7;
    float aU[8], aV[8];
#pragma unroll
    for (int u = 0; u < 8; ++u) { aU[u] = 0.f; aV[u] = 0.f; }
    for (int kk = 0; kk < DIN; ++kk) {
        float whi = W1[kk * DOUT + o];
        float wlo = W1[(DIN + kk) * DOUT + o];
        float wd = whi - wlo;
#pragma unroll
        for (int u = 0; u < 8; ++u) {
            float xv = xs[g * 8 + u][kk];
            aU[u] = fmaf(xv, wd, aU[u]);
            aV[u] = fmaf(xv, wlo, aV[u]);
        }
    }
    float bb = b1[o];
#pragma unroll
    for (int u = 0; u < 8; ++u) {
        int r = r0 + g * 8 + u;
        U[(size_t)r * DOUT + o] = aU[u] + bb;
        V[(size_t)r * DOUT + o] = aV[u];
    }
}

// K2: fused dist + per-lane sorted top-16.
// Lane owns row i (x_i in 64 VGPRs); j-loop is wave-uniform so x_j and sq[j]
// go through the scalar pipe (s_load broadcast). No LDS.
// Keys ((mono dist)<<32)|j give exact (dist asc, j asc) order == lax.top_k.
__global__ __launch_bounds__(256, 4) void k_dist_topk(const float* __restrict__ x,
                                                      const float* __restrict__ sq,
                                                      u64* __restrict__ pkeys) {
    int t = threadIdx.x;
    int chunk = blockIdx.x;
    int row = blockIdx.y * 256 + t;
    const float4* x4 = (const float4*)x;

    float4 xi[DIN / 4];
#pragma unroll
    for (int q = 0; q < DIN / 4; ++q) xi[q] = x4[(size_t)row * (DIN / 4) + q];
    float sqi = sq[row];

    u64 keys[KNN];                       // sorted ascending; keys[15] = max
#pragma unroll
    for (int s = 0; s < KNN; ++s) keys[s] = 0xFFFFFFFFFFFFFF00ull + (u64)s;

    int j0 = chunk * CHUNK;
    for (int jj = 0; jj < CHUNK; ++jj) {
        int j = j0 + jj;
        const float4* bj = x4 + (size_t)j * (DIN / 4);   // uniform -> s_load
        float s0 = 0.f, s1 = 0.f, s2 = 0.f, s3 = 0.f;
#pragma unroll
        for (int q = 0; q < DIN / 4; ++q) {
            float4 b = bj[q];
            s0 = fmaf(xi[q].x, b.x, s0); s1 = fmaf(xi[q].y, b.y, s1);
            s2 = fmaf(xi[q].z, b.z, s2); s3 = fmaf(xi[q].w, b.w, s3);
        }
        float d = (s0 + s1) + (s2 + s3);
        float dist = sqi + sq[j] - 2.0f * d;
        u64 key = ((u64)mono(dist) << 32) | (unsigned)j;
        if (key < keys[KNN - 1]) {
            keys[KNN - 1] = key;         // evict max, bubble into place
#pragma unroll
            for (int s = KNN - 2; s >= 0; --s) {
                u64 a = keys[s], b2 = keys[s + 1];
                bool sw = b2 < a;
                keys[s]     = sw ? b2 : a;
                keys[s + 1] = sw ? a : b2;
            }
        }
    }
#pragma unroll
    for (int s = 0; s < KNN; ++s)
        pkeys[(size_t)row * (NCHUNK * KNN) + chunk * KNN + s] = keys[s];
}

// K3: merge 512 candidates/row -> final 16 indices. One wave per row.
__global__ __launch_bounds__(256) void k_merge(const u64* __restrict__ pkeys,
                                               int* __restrict__ knn) {
    int wave = threadIdx.x >> 6, lane = threadIdx.x & 63;
    int row = blockIdx.x * 4 + wave;
    u64 k[8];
#pragma unroll
    for (int u = 0; u < 8; ++u)
        k[u] = pkeys[(size_t)row * (NCHUNK * KNN) + lane + 64 * u];
#pragma unroll
    for (int t = 0; t < KNN; ++t) {
        u64 m = k[0];
#pragma unroll
        for (int u = 1; u < 8; ++u) m = (k[u] < m) ? k[u] : m;
#pragma unroll
        for (int off = 32; off >= 1; off >>= 1) {
            u64 o = __shfl_xor(m, off, 64);
            m = (o < m) ? o : m;
        }
        if (lane == t) knn[row * KNN + t] = (int)(unsigned)(m & 0xFFFFFFFFull);
#pragma unroll
        for (int u = 0; u < 8; ++u)
            if (k[u] == m) k[u] = 0xFFFFFFFFFFFFFFFFull;
    }
}

// K4: agg[i] = mean_j relu(U[i]+V[knn[i][j]]);  out = agg@W2 + b2. 2 rows/block.
__global__ __launch_bounds__(256) void k_aggout(const float* __restrict__ U,
                                                const float* __restrict__ V,
                                                const int* __restrict__ knn,
                                                const float* __restrict__ W2,
                                                const float* __restrict__ b2,
                                                float* __restrict__ out) {
    __shared__ float ag[2][DOUT];
    int t = threadIdx.x;
    int r = t >> 7;
    int o = t & 127;
    int i = blockIdx.x * 2 + r;
    float u = U[(size_t)i * DOUT + o];
    const int* nb = knn + i * KNN;       // wave-uniform
    float acc = 0.f;
#pragma unroll
    for (int q = 0; q < KNN; ++q) {
        int j = nb[q];
        float v = V[(size_t)j * DOUT + o];
        acc += fmaxf(u + v, 0.0f);
    }
    ag[r][o] = acc * (1.0f / KNN);
    __syncthreads();
    float a2 = 0.f;
#pragma unroll 4
    for (int kk = 0; kk < DOUT; ++kk)
        a2 = fmaf(ag[r][kk], W2[kk * DOUT + o], a2);
    out[(size_t)i * DOUT + o] = a2 + b2[o];
}

extern "C" void kernel_launch(void* const* d_in, const int* in_sizes, int n_in,
                              void* d_out, int out_size, void* d_ws, size_t ws_size,
                              hipStream_t stream) {
    const float* x  = (const float*)d_in[0];
    const float* W1 = (const float*)d_in[1];
    const float* b1 = (const float*)d_in[2];
    const float* W2 = (const float*)d_in[3];
    const float* b2 = (const float*)d_in[4];
    float* out = (float*)d_out;

    char* ws = (char*)d_ws;
    float* sq    = (float*)ws;                                  // 32 KB
    u64*   pkeys = (u64*)(ws + 32768);                          // 33.5 MB
    float* U     = (float*)(ws + 32768 + (size_t)N * NCHUNK * KNN * 8);
    float* V     = U + (size_t)N * DOUT;                        // 4 MB each
    int*   knn   = (int*)(V + (size_t)N * DOUT);                // 512 KB
    // total ws use ~42 MB

    k_pre<<<N / ROWS_PRE, 256, 0, stream>>>(x, W1, b1, sq, U, V);
    k_dist_topk<<<dim3(NCHUNK, N / 256), 256, 0, stream>>>(x, sq, pkeys);
    k_merge<<<N / 4, 256, 0, stream>>>(pkeys, knn);
    k_aggout<<<N / 2, 256, 0, stream>>>(U, V, knn, W2, b2, out);
}

// Round 3
// 456.206 us; speedup vs baseline: 1.0250x; 1.0192x over previous
//
#include <hip/hip_runtime.h>

#define N 8192
#define DIN 64
#define DOUT 128
#define KNN 16
#define NCHUNK 32
#define CHUNK 256          /* N / NCHUNK */
#define PRE_NCHUNK 16
#define PRE_L 64           /* samples per pre-chunk; total sample m = 1024 */
#define PRE_STRIDE 8       /* sampled j = 8*s */
#define ROWS_PRE 16

typedef unsigned long long u64;

__device__ __forceinline__ unsigned mono(float f) {
    unsigned u = __float_as_uint(f);
    return (u & 0x80000000u) ? ~u : (u | 0x80000000u);
}

// K1: sq norms + U = x@(W1a-W1b)+b1, V = x@W1b (16 rows/block)
__global__ __launch_bounds__(256) void k_pre(const float* __restrict__ x,
                                             const float* __restrict__ W1,
                                             const float* __restrict__ b1,
                                             float* __restrict__ sq,
                                             float* __restrict__ U,
                                             float* __restrict__ V) {
    __shared__ float xs[ROWS_PRE][DIN];
    int t = threadIdx.x;
    int r0 = blockIdx.x * ROWS_PRE;
    const float4* x4 = (const float4*)x;
    ((float4*)xs)[t] = x4[(size_t)r0 * (DIN / 4) + t];
    __syncthreads();
    if (t < ROWS_PRE) {
        const float4* xr = (const float4*)xs[t];
        float s0 = 0.f, s1 = 0.f, s2 = 0.f, s3 = 0.f;
#pragma unroll
        for (int q = 0; q < DIN / 4; ++q) {
            float4 a = xr[q];
            s0 = fmaf(a.x, a.x, s0); s1 = fmaf(a.y, a.y, s1);
            s2 = fmaf(a.z, a.z, s2); s3 = fmaf(a.w, a.w, s3);
        }
        sq[r0 + t] = (s0 + s1) + (s2 + s3);
    }
    int o = t & 127, g = t >> 7;
    float aU[8], aV[8];
#pragma unroll
    for (int u = 0; u < 8; ++u) { aU[u] = 0.f; aV[u] = 0.f; }
    for (int kk = 0; kk < DIN; ++kk) {
        float whi = W1[kk * DOUT + o];
        float wlo = W1[(DIN + kk) * DOUT + o];
        float wd = whi - wlo;
#pragma unroll
        for (int u = 0; u < 8; ++u) {
            float xv = xs[g * 8 + u][kk];
            aU[u] = fmaf(xv, wd, aU[u]);
            aV[u] = fmaf(xv, wlo, aV[u]);
        }
    }
    float bb = b1[o];
#pragma unroll
    for (int u = 0; u < 8; ++u) {
        int r = r0 + g * 8 + u;
        U[(size_t)r * DOUT + o] = aU[u] + bb;
        V[(size_t)r * DOUT + o] = aV[u];
    }
}

// K2a: pre-sample scan. Each lane owns row, scans 64 sampled j's (stride 8),
// keeps exact top-16 via unconditional branchless shift-insert.
__global__ __launch_bounds__(256, 4) void k_presample(const float* __restrict__ x,
                                                      const float* __restrict__ sq,
                                                      u64* __restrict__ prekeys) {
    int t = threadIdx.x;
    int chunk = blockIdx.x;
    int row = blockIdx.y * 256 + t;
    const float4* x4 = (const float4*)x;
    float4 xi[DIN / 4];
#pragma unroll
    for (int q = 0; q < DIN / 4; ++q) xi[q] = x4[(size_t)row * (DIN / 4) + q];
    float sqi = sq[row];

    u64 keys[KNN];
#pragma unroll
    for (int s = 0; s < KNN; ++s) keys[s] = 0xFFFFFFFFFFFFFF00ull + (u64)s;

    for (int s = 0; s < PRE_L; ++s) {
        int j = (chunk * PRE_L + s) * PRE_STRIDE;
        const float4* bj = x4 + (size_t)j * (DIN / 4);   // uniform -> s_load
        float s0 = 0.f, s1 = 0.f, s2 = 0.f, s3 = 0.f;
#pragma unroll
        for (int q = 0; q < DIN / 4; ++q) {
            float4 b = bj[q];
            s0 = fmaf(xi[q].x, b.x, s0); s1 = fmaf(xi[q].y, b.y, s1);
            s2 = fmaf(xi[q].z, b.z, s2); s3 = fmaf(xi[q].w, b.w, s3);
        }
        float d = (s0 + s1) + (s2 + s3);
        float dist = sqi + sq[j] - 2.0f * d;
        u64 key = ((u64)mono(dist) << 32) | (unsigned)j;
#pragma unroll
        for (int s2i = 0; s2i < KNN; ++s2i) {            // shift-insert
            u64 a = keys[s2i];
            bool lt = key < a;
            keys[s2i] = lt ? key : a;
            key       = lt ? a : key;
        }
    }
#pragma unroll
    for (int s = 0; s < KNN; ++s)
        prekeys[(size_t)row * (PRE_NCHUNK * KNN) + chunk * KNN + s] = keys[s];
}

// K2b: tau[row] = hi32 of exact 16th-smallest sampled key. One wave per row.
__global__ __launch_bounds__(256) void k_tau(const u64* __restrict__ prekeys,
                                             unsigned* __restrict__ tauhi) {
    int wave = threadIdx.x >> 6, lane = threadIdx.x & 63;
    int row = blockIdx.x * 4 + wave;
    u64 k[4];
#pragma unroll
    for (int u = 0; u < 4; ++u)
        k[u] = prekeys[(size_t)row * 256 + lane + 64 * u];
    u64 m = 0;
#pragma unroll
    for (int t = 0; t < KNN; ++t) {
        m = k[0];
#pragma unroll
        for (int u = 1; u < 4; ++u) m = (k[u] < m) ? k[u] : m;
#pragma unroll
        for (int off = 32; off >= 1; off >>= 1) {
            u64 o = __shfl_xor(m, off, 64);
            m = (o < m) ? o : m;
        }
#pragma unroll
        for (int u = 0; u < 4; ++u)
            if (k[u] == m) k[u] = 0xFFFFFFFFFFFFFFFFull;
    }
    if (lane == 0) tauhi[row] = (unsigned)(m >> 32);     // m = 16th smallest
}

// K2c: gated full scan. Insert fires only when mono(dist) <= tau (~1/64 per
// lane). Chunk list = exact top-16 of {chunk candidates passing gate} which
// provably contains every global top-16 member in the chunk.
__global__ __launch_bounds__(256, 4) void k_dist_topk(const float* __restrict__ x,
                                                      const float* __restrict__ sq,
                                                      const unsigned* __restrict__ tauhi,
                                                      u64* __restrict__ pkeys) {
    int t = threadIdx.x;
    int chunk = blockIdx.x;
    int row = blockIdx.y * 256 + t;
    const float4* x4 = (const float4*)x;

    float4 xi[DIN / 4];
#pragma unroll
    for (int q = 0; q < DIN / 4; ++q) xi[q] = x4[(size_t)row * (DIN / 4) + q];
    float sqi = sq[row];
    unsigned th = tauhi[row];

    u64 keys[KNN];
#pragma unroll
    for (int s = 0; s < KNN; ++s) keys[s] = 0xFFFFFFFFFFFFFF00ull + (u64)s;

    int j0 = chunk * CHUNK;
    for (int jj = 0; jj < CHUNK; ++jj) {
        int j = j0 + jj;
        const float4* bj = x4 + (size_t)j * (DIN / 4);   // uniform -> s_load
        float s0 = 0.f, s1 = 0.f, s2 = 0.f, s3 = 0.f;
#pragma unroll
        for (int q = 0; q < DIN / 4; ++q) {
            float4 b = bj[q];
            s0 = fmaf(xi[q].x, b.x, s0); s1 = fmaf(xi[q].y, b.y, s1);
            s2 = fmaf(xi[q].z, b.z, s2); s3 = fmaf(xi[q].w, b.w, s3);
        }
        float d = (s0 + s1) + (s2 + s3);
        float dist = sqi + sq[j] - 2.0f * d;
        unsigned mh = mono(dist);
        if (mh <= th) {                                  // rare wave-branch
            u64 key = ((u64)mh << 32) | (unsigned)j;
#pragma unroll
            for (int s = 0; s < KNN; ++s) {              // shift-insert
                u64 a = keys[s];
                bool lt = key < a;
                keys[s] = lt ? key : a;
                key     = lt ? a : key;
            }
        }
    }
#pragma unroll
    for (int s = 0; s < KNN; ++s)
        pkeys[(size_t)row * (NCHUNK * KNN) + chunk * KNN + s] = keys[s];
}

// K3: merge 512 candidates/row -> final 16 indices. One wave per row.
__global__ __launch_bounds__(256) void k_merge(const u64* __restrict__ pkeys,
                                               int* __restrict__ knn) {
    int wave = threadIdx.x >> 6, lane = threadIdx.x & 63;
    int row = blockIdx.x * 4 + wave;
    u64 k[8];
#pragma unroll
    for (int u = 0; u < 8; ++u)
        k[u] = pkeys[(size_t)row * (NCHUNK * KNN) + lane + 64 * u];
#pragma unroll
    for (int t = 0; t < KNN; ++t) {
        u64 m = k[0];
#pragma unroll
        for (int u = 1; u < 8; ++u) m = (k[u] < m) ? k[u] : m;
#pragma unroll
        for (int off = 32; off >= 1; off >>= 1) {
            u64 o = __shfl_xor(m, off, 64);
            m = (o < m) ? o : m;
        }
        if (lane == t) knn[row * KNN + t] = (int)(unsigned)(m & 0xFFFFFFFFull);
#pragma unroll
        for (int u = 0; u < 8; ++u)
            if (k[u] == m) k[u] = 0xFFFFFFFFFFFFFFFFull;
    }
}

// K4: agg[i] = mean_j relu(U[i]+V[knn[i][j]]);  out = agg@W2 + b2.
__global__ __launch_bounds__(256) void k_aggout(const float* __restrict__ U,
                                                const float* __restrict__ V,
                                                const int* __restrict__ knn,
                                                const float* __restrict__ W2,
                                                const float* __restrict__ b2,
                                                float* __restrict__ out) {
    __shared__ float ag[2][DOUT];
    int t = threadIdx.x;
    int r = t >> 7;
    int o = t & 127;
    int i = blockIdx.x * 2 + r;
    float u = U[(size_t)i * DOUT + o];
    const int* nb = knn + i * KNN;       // wave-uniform
    float acc = 0.f;
#pragma unroll
    for (int q = 0; q < KNN; ++q) {
        int j = nb[q];
        float v = V[(size_t)j * DOUT + o];
        acc += fmaxf(u + v, 0.0f);
    }
    ag[r][o] = acc * (1.0f / KNN);
    __syncthreads();
    float a2 = 0.f;
#pragma unroll 4
    for (int kk = 0; kk < DOUT; ++kk)
        a2 = fmaf(ag[r][kk], W2[kk * DOUT + o], a2);
    out[(size_t)i * DOUT + o] = a2 + b2[o];
}

extern "C" void kernel_launch(void* const* d_in, const int* in_sizes, int n_in,
                              void* d_out, int out_size, void* d_ws, size_t ws_size,
                              hipStream_t stream) {
    const float* x  = (const float*)d_in[0];
    const float* W1 = (const float*)d_in[1];
    const float* b1 = (const float*)d_in[2];
    const float* W2 = (const float*)d_in[3];
    const float* b2 = (const float*)d_in[4];
    float* out = (float*)d_out;

    char* ws = (char*)d_ws;
    float*    sq      = (float*)ws;                               // 32 KB
    u64*      pkeys   = (u64*)(ws + 32768);                       // 33.55 MB
    u64*      prekeys = pkeys;                                    // aliased: dead before pkeys written
    unsigned* tauhi   = (unsigned*)(ws + 32768 + (size_t)N * NCHUNK * KNN * 8);  // 32 KB
    float*    U       = (float*)((char*)tauhi + 32768);           // 4 MB
    float*    V       = U + (size_t)N * DOUT;                     // 4 MB
    int*      knn     = (int*)(V + (size_t)N * DOUT);             // 512 KB
    // total ws use ~42.6 MB

    k_pre<<<N / ROWS_PRE, 256, 0, stream>>>(x, W1, b1, sq, U, V);
    k_presample<<<dim3(PRE_NCHUNK, N / 256), 256, 0, stream>>>(x, sq, prekeys);
    k_tau<<<N / 4, 256, 0, stream>>>(prekeys, tauhi);
    k_dist_topk<<<dim3(NCHUNK, N / 256), 256, 0, stream>>>(x, sq, tauhi, pkeys);
    k_merge<<<N / 4, 256, 0, stream>>>(pkeys, knn);
    k_aggout<<<N / 2, 256, 0, stream>>>(U, V, knn, W2, b2, out);
}